// Round 10
// baseline (1021.642 us; speedup 1.0000x reference)
//
#include <hip/hip_runtime.h>
#include <hip/hip_bf16.h>
#include <math.h>

#define A_ 4
#define M_ 32
#define S_ 48000
#define L_ 16000
#define NB_ 8
#define BIN_ 64
#define TWO_PI_F 6.28318530717958647692f
#define INV_SR (1.0f / 48000.0f)
#define NCHUNK 47            /* ceil(48000/1024) */
#define NROW 128             /* A_*M_ */
#define SBPAD 16000          /* zeros before signal in sigbf */
#define SBLEN 64256          /* 16000 + 48000 + 256 tail pad */
#define NKT 501              /* K blocks of 32 taps (w reaches 1000 incl.) */
#define MB_ 64               /* output u-rows per conv block */
#define CB_PER_A 47          /* 47*64 = 3008 u-rows = 48128 >= 48000 */

/* ---- workspace layout (bytes) ---- */
#define CST_OFF    0u                /* 232 floats */
#define SIG_OFF    1024u             /* float[4*48000] = 768000 */
#define SIGBF_OFF  769024u           /* ushort[4*64256] = 514048 */
#define FRAGB_OFF  1283072u          /* ushort[4*501*64*8] = 2052096 */
#define FLAG_OFF   3335168u          /* int[128*47] = 24064 */
#define AGGD_OFF   3359232u          /* double[6016] = 48128 */
#define AGGF_OFF   3407360u
#define INCLD_OFF  3455488u
#define INCLF_OFF  3503616u
#define WS_NEEDED  3551744u

typedef __attribute__((ext_vector_type(8))) short bf16x8;
typedef __attribute__((ext_vector_type(4))) float f32x4;

__device__ __forceinline__ float softplusf(float x) {
    float t = __expf(-fabsf(x));
    return fmaxf(x, 0.f) + __logf(1.f + t);
}
__device__ __forceinline__ unsigned short bfbits(float v) {
    __hip_bfloat16 h = __float2bfloat16(v);
    return *(unsigned short*)&h;
}

/* ---------- tiny precompute ---------- */
__global__ void k_precompute(const float* __restrict__ flin_p,
                             const float* __restrict__ alpha_p,
                             const float* __restrict__ beta_p,
                             const float* __restrict__ amp_v,
                             float* __restrict__ cst) {
    __shared__ float sF[NB_], sA[BIN_], sB[BIN_];
    int tid = threadIdx.x;
    if (tid < NB_) {
        double lf = log(20.0) + (double)tid * ((log(8000.0) - log(20.0)) / 7.0);
        float v = (float)exp(lf);
        sF[tid] = v; cst[tid] = v;
    }
    if (tid < BIN_) {
        double la = log(0.3) + (double)tid * ((log(300.0) - log(0.3)) / 63.0);
        sA[tid] = (float)exp(la);
        double lb = log(1e-10) + (double)tid * ((log(1e-7) - log(1e-10)) / 63.0);
        sB[tid] = (float)exp(lb);
    }
    __syncthreads();
    if (tid < M_) {
        float sum = 0.f, dot = 0.f;
        for (int i = 0; i < NB_; ++i) {
            float sp = softplusf(flin_p[tid * NB_ + i]);
            sum += sp; dot = fmaf(sp, sF[i], dot);
        }
        cst[8 + tid] = dot / sum;
        sum = 0.f; dot = 0.f;
        for (int i = 0; i < BIN_; ++i) {
            float sp = softplusf(alpha_p[tid * BIN_ + i]);
            sum += sp; dot = fmaf(sp, sA[i], dot);
        }
        cst[40 + tid] = dot / sum;
        sum = 0.f; dot = 0.f;
        for (int i = 0; i < BIN_; ++i) {
            float sp = softplusf(beta_p[tid * BIN_ + i]);
            sum += sp; dot = fmaf(sp, sB[i], dot);
        }
        cst[72 + tid] = dot / sum;
    }
    if (tid < A_ * M_) {
        float x = amp_v[tid];
        float sg = 1.f / (1.f + __expf(-x));
        cst[104 + tid] = 2.f * __expf(2.30258509299404568402f * __logf(sg)) + 1e-7f;
    }
}

/* ---------- forces Toeplitz fragments (bf16, pre-swizzled) ---------- */
__global__ __launch_bounds__(256) void k_fragB(const float* __restrict__ forces,
                                               unsigned short* __restrict__ fragB) {
    int t = blockIdx.x * 256 + threadIdx.x;      /* (a, kk, lane): 4*501*64 */
    if (t >= A_ * NKT * 64) return;
    int l  = t & 63;
    int kk = (t >> 6) % NKT;
    int a  = t / (NKT * 64);
    int v  = l & 15, hq = l >> 4;
    unsigned short hi[8];
#pragma unroll
    for (int j = 0; j < 8; ++j) {
        int k = hq * 8 + j;
        int r = k & 15, hw = k >> 4;
        int fj = 32 * kk + 16 * hw + v - r;      /* B[k][v] = f[16w + v - r] */
        float fv = (fj >= 0 && fj < L_) ? forces[a * L_ + fj] : 0.f;
        hi[j] = bfbits(fv);
    }
    uint4 ph;
    ph.x = (unsigned)hi[0] | ((unsigned)hi[1] << 16);
    ph.y = (unsigned)hi[2] | ((unsigned)hi[3] << 16);
    ph.z = (unsigned)hi[4] | ((unsigned)hi[5] << 16);
    ph.w = (unsigned)hi[6] | ((unsigned)hi[7] << 16);
    ((uint4*)fragB)[t] = ph;
}

/* ---------- fused scan: increments + decoupled-lookback cumsum + eval ---------- */
__global__ __launch_bounds__(256) void k_scan(const float* __restrict__ nl,
                                              const float* __restrict__ cst,
                                              float* __restrict__ sig,
                                              double* aggd, double* aggf,
                                              double* incld, double* inclf,
                                              int* flags) {
    int chunk = blockIdx.x, row = blockIdx.y, tid = threadIdx.x;
    int m = row & 31, a = row >> 5;

    float Fv[8];
#pragma unroll
    for (int i = 0; i < 8; ++i) Fv[i] = cst[i];
    float flin = cst[8 + m], al = cst[40 + m], be = cst[72 + m];
    float amp = cst[104 + row];

    const float4* nl4 = (const float4*)nl;
    int s0 = chunk * 1024 + tid * 4;
    float lpx[4], lpy[4];
    float rx = 0.f, ry = 0.f;
#pragma unroll
    for (int k = 0; k < 4; ++k) {
        int s = s0 + k;
        float vx = 0.f, vy = 0.f;
        if (s < S_) {
            size_t off = ((size_t)row * S_ + s) * 2;
            float4 x0 = nl4[off];
            float4 x1 = nl4[off + 1];
            float xs[8] = {x0.x, x0.y, x0.z, x0.w, x1.x, x1.y, x1.z, x1.w};
            float sum = 0.f, dot = 0.f;
#pragma unroll
            for (int i = 0; i < 8; ++i) {
                float sp = softplusf(xs[i]);
                sum += sp; dot = fmaf(sp, Fv[i], dot);
            }
            float und = flin + 0.3f * (dot / sum);
            float w = TWO_PI_F * und;
            float lbd = w * w;
            float damp = 0.5f * fmaf(be, lbd, al);
            float freq = sqrtf(lbd - damp * damp) * (1.0f / TWO_PI_F);
            vx = damp * INV_SR;
            vy = freq * INV_SR;
        }
        rx += vx; lpx[k] = rx;
        ry += vy; lpy[k] = ry;
    }

    __shared__ double sx[256], sy[256];
    __shared__ double sPd, sPf;
    sx[tid] = (double)rx; sy[tid] = (double)ry;
    __syncthreads();
    for (int o = 1; o < 256; o <<= 1) {
        double ax = (tid >= o) ? sx[tid - o] : 0.0;
        double ay = (tid >= o) ? sy[tid - o] : 0.0;
        __syncthreads();
        sx[tid] += ax; sy[tid] += ay;
        __syncthreads();
    }

    if (tid == 0) {
        int idx = row * NCHUNK + chunk;           /* == flat dispatch id order */
        double Td = sx[255], Tf = sy[255];
        double Pd = 0.0, Pf = 0.0;
        if (chunk == 0) {
            __hip_atomic_store(&incld[idx], Td, __ATOMIC_RELAXED, __HIP_MEMORY_SCOPE_AGENT);
            __hip_atomic_store(&inclf[idx], Tf, __ATOMIC_RELAXED, __HIP_MEMORY_SCOPE_AGENT);
            __hip_atomic_store(&flags[idx], 2, __ATOMIC_RELEASE, __HIP_MEMORY_SCOPE_AGENT);
        } else {
            __hip_atomic_store(&aggd[idx], Td, __ATOMIC_RELAXED, __HIP_MEMORY_SCOPE_AGENT);
            __hip_atomic_store(&aggf[idx], Tf, __ATOMIC_RELAXED, __HIP_MEMORY_SCOPE_AGENT);
            __hip_atomic_store(&flags[idx], 1, __ATOMIC_RELEASE, __HIP_MEMORY_SCOPE_AGENT);
            int i = idx - 1;
            while (1) {
                int fl = __hip_atomic_load(&flags[i], __ATOMIC_ACQUIRE, __HIP_MEMORY_SCOPE_AGENT);
                if (fl == 0) { __builtin_amdgcn_s_sleep(1); continue; }
                if (fl == 2) {
                    Pd += __hip_atomic_load(&incld[i], __ATOMIC_RELAXED, __HIP_MEMORY_SCOPE_AGENT);
                    Pf += __hip_atomic_load(&inclf[i], __ATOMIC_RELAXED, __HIP_MEMORY_SCOPE_AGENT);
                    break;
                }
                Pd += __hip_atomic_load(&aggd[i], __ATOMIC_RELAXED, __HIP_MEMORY_SCOPE_AGENT);
                Pf += __hip_atomic_load(&aggf[i], __ATOMIC_RELAXED, __HIP_MEMORY_SCOPE_AGENT);
                --i;
            }
            __hip_atomic_store(&incld[idx], Pd + Td, __ATOMIC_RELAXED, __HIP_MEMORY_SCOPE_AGENT);
            __hip_atomic_store(&inclf[idx], Pf + Tf, __ATOMIC_RELAXED, __HIP_MEMORY_SCOPE_AGENT);
            __hip_atomic_store(&flags[idx], 2, __ATOMIC_RELEASE, __HIP_MEMORY_SCOPE_AGENT);
        }
        sPd = Pd; sPf = Pf;
    }
    __syncthreads();

    double ex = sPd + ((tid > 0) ? sx[tid - 1] : 0.0);
    double ey = sPf + ((tid > 0) ? sy[tid - 1] : 0.0);
#pragma unroll
    for (int k = 0; k < 4; ++k) {
        int s = s0 + k;
        if (s < S_) {
            double cd = ex + (double)lpx[k];
            if (cd < 16.0) {
                double cf = ey + (double)lpy[k];
                float ph = (float)(cf - floor(cf));
                float val = amp * __expf(-(float)cd) * __sinf(TWO_PI_F * ph);
                atomicAdd(&sig[a * S_ + s], val);
            }
        }
    }
}

/* ---------- sig f32 -> padded bf16 ---------- */
__global__ __launch_bounds__(256) void k_convert(const float* __restrict__ sig,
                                                 unsigned short* __restrict__ sigbf) {
    int i = blockIdx.x * 256 + threadIdx.x;      /* 4*64256 = 257024 */
    if (i >= A_ * SBLEN) return;
    int a = i / SBLEN, p = i - a * SBLEN;
    int s = p - SBPAD;
    float v = (s >= 0 && s < S_) ? sig[a * S_ + s] : 0.f;
    sigbf[i] = bfbits(v);
}

/* ---------- conv: block-Toeplitz MFMA GEMM, 64 rows/block (B reused x4) ---------- */
__global__ __launch_bounds__(512) void k_conv(const unsigned short* __restrict__ sigbf,
                                              const unsigned short* __restrict__ fragB,
                                              float* __restrict__ out) {
    int a   = blockIdx.y;
    int ub0 = blockIdx.x * MB_;                  /* first u-row of this block */
    int tid = threadIdx.x;
    int wv  = tid >> 6;                          /* wave 0..7 */
    int l   = tid & 63;
    int du = l & 15, hq = l >> 4, hw = hq >> 1, hr = hq & 1;

    int nkk = (ub0 >> 1) + 33;                   /* covers rows through ub0+63 */
    if (nkk > NKT) nkk = NKT;

    const unsigned short* sig_a = sigbf + (size_t)a * SBLEN;
    int ebase = SBPAD + 16 * (ub0 + du) - 16 * hw + 8 * hr;
    const unsigned short* fB = fragB + (((size_t)a * NKT) * 64 + l) * 8;

    f32x4 acc[4];
#pragma unroll
    for (int m = 0; m < 4; ++m) acc[m] = (f32x4){0.f, 0.f, 0.f, 0.f};

    for (int kk = wv; kk < nkk; kk += 8) {
        bf16x8 bh = *(const bf16x8*)(fB + (size_t)kk * 512);
        int e = ebase - 32 * kk;
#pragma unroll
        for (int m = 0; m < 4; ++m) {
            bf16x8 ah = *(const bf16x8*)(sig_a + e + 256 * m);   /* u += 16m */
            acc[m] = __builtin_amdgcn_mfma_f32_16x16x32_bf16(ah, bh, acc[m], 0, 0, 0);
        }
    }

    __shared__ float red[8][1024];               /* 32 KB */
#pragma unroll
    for (int m = 0; m < 4; ++m)
#pragma unroll
        for (int r = 0; r < 4; ++r)              /* C: row=(l>>4)*4+r, col=l&15 */
            red[wv][m * 256 + (hq * 4 + r) * 16 + (l & 15)] = acc[m][r];
    __syncthreads();

#pragma unroll
    for (int rep = 0; rep < 2; ++rep) {
        int o = tid + rep * 512;
        float s = 0.f;
#pragma unroll
        for (int w2 = 0; w2 < 8; ++w2) s += red[w2][o];
        int t = 16 * ub0 + o;
        if (t < S_) out[(size_t)a * S_ + t] = s;
    }
}

extern "C" void kernel_launch(void* const* d_in, const int* in_sizes, int n_in,
                              void* d_out, int out_size, void* d_ws, size_t ws_size,
                              hipStream_t stream) {
    if (ws_size < (size_t)WS_NEEDED) return;

    const float* flin_p  = (const float*)d_in[0];
    const float* nl_p    = (const float*)d_in[1];
    const float* alpha_p = (const float*)d_in[2];
    const float* beta_p  = (const float*)d_in[3];
    const float* amp_v   = (const float*)d_in[4];
    const float* forces  = (const float*)d_in[5];
    float* out = (float*)d_out;

    char* ws = (char*)d_ws;
    float*          cst    = (float*)(ws + CST_OFF);
    float*          sig    = (float*)(ws + SIG_OFF);
    unsigned short* sigbf  = (unsigned short*)(ws + SIGBF_OFF);
    unsigned short* fragB  = (unsigned short*)(ws + FRAGB_OFF);
    int*            flags  = (int*)(ws + FLAG_OFF);
    double*         aggd   = (double*)(ws + AGGD_OFF);
    double*         aggf   = (double*)(ws + AGGF_OFF);
    double*         incld  = (double*)(ws + INCLD_OFF);
    double*         inclf  = (double*)(ws + INCLF_OFF);

    hipMemsetAsync(sig, 0, (size_t)A_ * S_ * sizeof(float), stream);
    hipMemsetAsync(flags, 0, (size_t)NROW * NCHUNK * sizeof(int), stream);

    hipLaunchKernelGGL(k_precompute, dim3(1), dim3(256), 0, stream,
                       flin_p, alpha_p, beta_p, amp_v, cst);
    hipLaunchKernelGGL(k_fragB, dim3(501), dim3(256), 0, stream, forces, fragB);
    hipLaunchKernelGGL(k_scan, dim3(NCHUNK, NROW), dim3(256), 0, stream,
                       nl_p, cst, sig, aggd, aggf, incld, inclf, flags);
    hipLaunchKernelGGL(k_convert, dim3(1004), dim3(256), 0, stream, sig, sigbf);
    hipLaunchKernelGGL(k_conv, dim3(CB_PER_A, A_), dim3(512), 0, stream,
                       sigbf, fragB, out);
}